// Round 4
// baseline (333.064 us; speedup 1.0000x reference)
//
#include <hip/hip_runtime.h>

// YOLO post-process, 3 kernels:
//  scan : per (img, 1600-anchor chunk) exact streaming top-64, float4 loads,
//         shuffle-based seed threshold, LDS candidate buffer
//  merge: per (img, level) sort chunk top-64s -> level top-64, decode boxes
//  nms  : per img stable sort 192 + parallel IoU bit-matrix + greedy bit-sweep

#define NUM_CLASSES 5
#define CONF_THRESH 0.6f
#define NMS_THRESH  0.2f
#define TOPK   64
#define BATCH  128
#define TOTK   192
#define NCH    21      // per image: 16 (lvl0) + 4 (lvl1) + 1 (lvl2), 1600 anchors each
#define CHUNK  1600
#define SCAP   2048    // LDS candidate buffer (u64)
#define SOFT   768     // compact when cnt exceeds this; SOFT + 1280 <= SCAP

typedef unsigned long long u64;
typedef unsigned int u32;

// Descending bitonic sort of k[0..m) (m pow2), block-cooperative.
// First action is a barrier (covers preceding LDS writes); ends with a barrier.
__device__ void bitonic_desc(u64* k, int m) {
  for (int kk = 2; kk <= m; kk <<= 1) {
    for (int j = kk >> 1; j > 0; j >>= 1) {
      __syncthreads();
      for (int i = threadIdx.x; i < m; i += blockDim.x) {
        int ixj = i ^ j;
        if (ixj > i) {
          u64 a = k[i], b = k[ixj];
          bool sw = ((i & kk) == 0) ? (a < b) : (a > b);
          if (sw) { k[i] = b; k[ixj] = a; }
        }
      }
    }
  }
  __syncthreads();
}

// In-register bitonic sort of 64 values across one wave, descending by lane.
// No barriers; 21 shfl_xor stages.
__device__ inline u64 wave_sort64_desc(u64 v, int lane) {
  #pragma unroll
  for (int k = 2; k <= 64; k <<= 1) {
    #pragma unroll
    for (int j = k >> 1; j > 0; j >>= 1) {
      u64 o = __shfl_xor(v, j, 64);
      bool keepMax = (((lane & k) == 0) != ((lane & j) != 0));
      v = keepMax ? (v > o ? v : o) : (v < o ? v : o);
    }
  }
  return v;
}

// score = sqrt(sigmoid(obj)*sigmoid(cls)); key = (score_bits<<32) | ~idx
// reproduces lax.top_k order (value desc, index asc). Bit-exact vs numpy
// (absmax 0.0 in R2/R3) -- do not alter the float expressions.
__device__ inline u64 score_key(float so, float cv, int idx) {
  float sc = 1.0f / (1.0f + expf(-cv));
  float s  = sqrtf(__fmul_rn(so, sc));
  return ((u64)__float_as_uint(s) << 32) | (u32)(~(u32)idx);
}

__device__ inline float sigmoidf(float x) { return 1.0f / (1.0f + expf(-x)); }

__global__ __launch_bounds__(256) void scan_kernel(
    const float* __restrict__ obj8,  const float* __restrict__ cls8,
    const float* __restrict__ obj16, const float* __restrict__ cls16,
    const float* __restrict__ obj32, const float* __restrict__ cls32,
    u64* __restrict__ ws_part) {
  __shared__ u64 keys[SCAP];
  __shared__ int cnt;
  __shared__ u64 sthr[4];

  const int bx  = blockIdx.x;
  const int img = bx / NCH;
  const int c   = bx - img * NCH;
  const int t   = threadIdx.x;
  const int lane = t & 63, wv = t >> 6;

  const float *obj, *cls;
  int hw, off;
  if (c < 16)      { obj = obj8;  cls = cls8;  hw = 25600; off = c * CHUNK; }
  else if (c < 20) { obj = obj16; cls = cls16; hw = 6400;  off = (c - 16) * CHUNK; }
  else             { obj = obj32; cls = cls32; hw = 1600;  off = 0; }
  obj += (size_t)img * hw + off;
  cls += ((size_t)img * hw + off) * NUM_CLASSES;

  // ---- tile 1: anchors [0,1024), thread t owns 4 consecutive anchors ----
  u64 kk[20];
  {
    const float4* c4 = (const float4*)cls + (size_t)t * 5;
    float4 q[5];
    q[0] = c4[0]; q[1] = c4[1]; q[2] = c4[2]; q[3] = c4[3]; q[4] = c4[4];
    float4 ov = ((const float4*)obj)[t];
    const float* cv = (const float*)q;
    float os[4] = { sigmoidf(ov.x), sigmoidf(ov.y), sigmoidf(ov.z), sigmoidf(ov.w) };
    int ga0 = off + 4 * t;
    #pragma unroll
    for (int a = 0; a < 4; ++a)
      #pragma unroll
      for (int j = 0; j < 5; ++j)
        kk[a * 5 + j] = score_key(os[a], cv[a * 5 + j], (ga0 + a) * NUM_CLASSES + j);
  }
  u64 mx = kk[0];
  #pragma unroll
  for (int i = 1; i < 20; ++i) if (kk[i] > mx) mx = kk[i];
  // seed threshold: min over waves of (wave's 16th-largest thread-max).
  // Each wave has >=16 real keys >= its 16th -> >=64 keys >= min across 4 waves.
  u64 srt = wave_sort64_desc(mx, lane);
  if (lane == 15) sthr[wv] = srt;
  if (t == 0) cnt = 0;
  __syncthreads();
  u64 thr;
  {
    u64 a0 = sthr[0], a1 = sthr[1], a2 = sthr[2], a3 = sthr[3];
    u64 mn = a0 < a1 ? a0 : a1;
    u64 mn2 = a2 < a3 ? a2 : a3;
    thr = (mn < mn2 ? mn : mn2) - 1ull;   // push iff key > thr  (key >= seed)
  }

  // ---- 8 push rounds: r<4 from tile 1 regs; r>=4 from tile 2 (576 anchors) ----
  int cs = 0;
  for (int r = 0; r < 8; ++r) {
    if (r == 4 && t < 144) {   // uniform branch on r; predicated work on t
      const float4* c4 = (const float4*)cls + 1280 + (size_t)t * 5;  // anchor 1024 -> float4 1280
      float4 q[5];
      q[0] = c4[0]; q[1] = c4[1]; q[2] = c4[2]; q[3] = c4[3]; q[4] = c4[4];
      float4 ov = ((const float4*)obj)[256 + t];
      const float* cv = (const float*)q;
      float os[4] = { sigmoidf(ov.x), sigmoidf(ov.y), sigmoidf(ov.z), sigmoidf(ov.w) };
      int ga0 = off + 1024 + 4 * t;
      #pragma unroll
      for (int a = 0; a < 4; ++a)
        #pragma unroll
        for (int j = 0; j < 5; ++j)
          kk[a * 5 + j] = score_key(os[a], cv[a * 5 + j], (ga0 + a) * NUM_CLASSES + j);
    }
    bool active = (r < 4) || (t < 144);
    if (active) {
      int b = (r & 3) * 5;
      #pragma unroll
      for (int j = 0; j < 5; ++j) {
        u64 key = kk[b + j];
        if (key > thr) { int p = atomicAdd(&cnt, 1); if (p < SCAP) keys[p] = key; }
      }
    }
    __syncthreads();
    cs = cnt;
    __syncthreads();              // uniform snapshot before anyone pushes again
    if (cs > SOFT) {              // rare: compact to top-64, tighten threshold
      int m = 64; while (m < cs) m <<= 1;
      for (int i = cs + t; i < m; i += 256) keys[i] = 0ull;
      bitonic_desc(keys, m);
      if (t == 0) cnt = TOPK;
      u64 nt = keys[TOPK - 1];
      __syncthreads();            // cnt=64 visible before next round's atomics
      thr = nt;                   // push iff key > 64th-so-far (keys unique)
      cs = TOPK;
    }
  }

  // ---- final sort, emit chunk top-64 (cnt >= 64 guaranteed by seed) ----
  {
    int m = 64; while (m < cs) m <<= 1;
    for (int i = cs + t; i < m; i += 256) keys[i] = 0ull;
    bitonic_desc(keys, m);
  }
  if (t < TOPK) ws_part[(size_t)bx * TOPK + t] = keys[t];
}

// One block per (img, level): sort nchunk*64 keys, keep 64, decode boxes.
__global__ __launch_bounds__(256) void merge_kernel(
    const u64* __restrict__ ws_part,
    const float* __restrict__ reg8, const float* __restrict__ reg16, const float* __restrict__ reg32,
    float* __restrict__ ws_score, int* __restrict__ ws_label, float* __restrict__ ws_box) {
  __shared__ u64 keys[1024];
  const int bx  = blockIdx.x;
  const int img = bx / 3;
  const int lvl = bx - img * 3;
  const int tid = threadIdx.x;

  const float* reg; int nchunk, cbase, w, hw; float stride;
  if (lvl == 0)      { reg = reg8;  nchunk = 16; cbase = 0;  w = 160; hw = 25600; stride = 8.0f;  }
  else if (lvl == 1) { reg = reg16; nchunk = 4;  cbase = 16; w = 80;  hw = 6400;  stride = 16.0f; }
  else               { reg = reg32; nchunk = 1;  cbase = 20; w = 40;  hw = 1600;  stride = 32.0f; }
  reg += (size_t)img * hw * 4;
  const int nk = nchunk * TOPK;                     // 1024 / 256 / 64 (pow2)
  const u64* src = ws_part + ((size_t)img * NCH + cbase) * TOPK;
  for (int i = tid; i < nk; i += 256) keys[i] = src[i];
  bitonic_desc(keys, nk);

  if (tid < TOPK) {
    u64 key = keys[tid];
    float s = __uint_as_float((u32)(key >> 32));
    u32 idx = ~((u32)key);
    int a = (int)(idx / NUM_CLASSES);
    int c = (int)(idx - (u32)a * NUM_CLASSES);
    int ix = a % w, iy = a / w;
    float ax = __fmul_rn((float)ix + 0.5f, stride);
    float ay = __fmul_rn((float)iy + 0.5f, stride);
    float r0 = reg[a*4+0], r1 = reg[a*4+1], r2 = reg[a*4+2], r3 = reg[a*4+3];
    float cx = __fadd_rn(__fmul_rn(r0, stride), ax);
    float cy = __fadd_rn(__fmul_rn(r1, stride), ay);
    float wd = __fmul_rn(expf(r2), stride);
    float ht = __fmul_rn(expf(r3), stride);
    float x1 = __fsub_rn(cx, __fmul_rn(0.5f, wd));
    float y1 = __fsub_rn(cy, __fmul_rn(0.5f, ht));
    float x2 = __fadd_rn(cx, __fmul_rn(0.5f, wd));
    float y2 = __fadd_rn(cy, __fmul_rn(0.5f, ht));
    int gi = img * TOTK + lvl * TOPK + tid;
    ws_score[gi] = s;
    ws_label[gi] = c;
    ws_box[gi*4+0] = x1; ws_box[gi*4+1] = y1;
    ws_box[gi*4+2] = x2; ws_box[gi*4+3] = y2;
  }
}

// One block (192 threads) per image.
__global__ __launch_bounds__(192) void nms_kernel(
    const float* __restrict__ ws_score, const int* __restrict__ ws_label,
    const float* __restrict__ ws_box, float* __restrict__ out) {
  __shared__ u64   skeys[256];
  __shared__ int   slb[TOTK];
  __shared__ float sbx[TOTK * 4];
  __shared__ float sX1[TOTK], sY1[TOTK], sX2[TOTK], sY2[TOTK], sA[TOTK];
  __shared__ u64   rows[TOTK * 3];
  __shared__ u64   svalid[3];
  __shared__ u64   skeep[3];
  __shared__ float lmarr[3];

  const int t   = threadIdx.x;
  const int img = blockIdx.x;

  {
    int gi = img * TOTK + t;
    float sc = ws_score[gi];
    int   lb = ws_label[gi];
    float b0 = ws_box[gi*4+0], b1 = ws_box[gi*4+1];
    float b2 = ws_box[gi*4+2], b3 = ws_box[gi*4+3];
    slb[t] = lb;
    sbx[t*4+0] = b0; sbx[t*4+1] = b1; sbx[t*4+2] = b2; sbx[t*4+3] = b3;
    skeys[t] = ((u64)__float_as_uint(sc) << 32) | (u32)(~(u32)t);
    if (t < 64) skeys[TOTK + t] = 0ull;
    float lm = fmaxf(fmaxf(fabsf(b0), fabsf(b1)), fmaxf(fabsf(b2), fabsf(b3)));
    #pragma unroll
    for (int d = 32; d > 0; d >>= 1) lm = fmaxf(lm, __shfl_xor(lm, d, 64));
    if ((t & 63) == 0) lmarr[t >> 6] = lm;
  }
  bitonic_desc(skeys, 256);

  const float lmAll = fmaxf(fmaxf(lmarr[0], lmarr[1]), lmarr[2]);
  const float offscale = __fadd_rn(__fmul_rn(2.0f, lmAll), 1.0f);

  u64 key = skeys[t];
  int p = (int)(~((u32)key)) & 255;
  float sc_r = __uint_as_float((u32)(key >> 32));
  int lb_r = slb[p];
  float off = __fmul_rn((float)lb_r, offscale);
  float X1 = __fadd_rn(sbx[p*4+0], off), Y1 = __fadd_rn(sbx[p*4+1], off);
  float X2 = __fadd_rn(sbx[p*4+2], off), Y2 = __fadd_rn(sbx[p*4+3], off);
  float A  = __fmul_rn(__fsub_rn(X2, X1), __fsub_rn(Y2, Y1));
  sX1[t] = X1; sY1[t] = Y1; sX2[t] = X2; sY2[t] = Y2; sA[t] = A;
  {
    u64 bal = __ballot(sc_r > CONF_THRESH);
    if ((t & 63) == 0) svalid[t >> 6] = bal;
  }
  __syncthreads();

  {
    u64 r0 = 0, r1 = 0, r2 = 0;
    for (int j = t + 1; j < TOTK; ++j) {
      float xx1 = fmaxf(X1, sX1[j]);
      float yy1 = fmaxf(Y1, sY1[j]);
      float xx2 = fminf(X2, sX2[j]);
      float yy2 = fminf(Y2, sY2[j]);
      float wv = fmaxf(1e-10f, __fsub_rn(xx2, xx1));
      float hv = fmaxf(1e-10f, __fsub_rn(yy2, yy1));
      float inter = __fmul_rn(wv, hv);
      float den = __fsub_rn(__fadd_rn(A, sA[j]), inter);
      float iou = __fdiv_rn(inter, den);
      if (iou > NMS_THRESH) {
        u64 b = 1ull << (j & 63);
        int wd = j >> 6;
        r0 |= (wd == 0) ? b : 0ull;
        r1 |= (wd == 1) ? b : 0ull;
        r2 |= (wd == 2) ? b : 0ull;
      }
    }
    rows[t*3+0] = r0; rows[t*3+1] = r1; rows[t*3+2] = r2;
  }
  __syncthreads();

  if (t < 64) {
    u64 k0 = svalid[0], k1 = svalid[1], k2 = svalid[2];
    #pragma unroll 4
    for (int i = 0; i < 64; ++i) {
      u64 m0 = rows[i*3+0], m1 = rows[i*3+1], m2 = rows[i*3+2];
      u64 sel = 0ull - ((k0 >> i) & 1ull);
      k0 &= ~(m0 & sel); k1 &= ~(m1 & sel); k2 &= ~(m2 & sel);
    }
    #pragma unroll 4
    for (int i = 0; i < 64; ++i) {
      int r = 64 + i;
      u64 m0 = rows[r*3+0], m1 = rows[r*3+1], m2 = rows[r*3+2];
      u64 sel = 0ull - ((k1 >> i) & 1ull);
      k0 &= ~(m0 & sel); k1 &= ~(m1 & sel); k2 &= ~(m2 & sel);
    }
    #pragma unroll 4
    for (int i = 0; i < 64; ++i) {
      int r = 128 + i;
      u64 m0 = rows[r*3+0], m1 = rows[r*3+1], m2 = rows[r*3+2];
      u64 sel = 0ull - ((k2 >> i) & 1ull);
      k0 &= ~(m0 & sel); k1 &= ~(m1 & sel); k2 &= ~(m2 & sel);
    }
    if (t == 0) { skeep[0] = k0; skeep[1] = k1; skeep[2] = k2; }
  }
  __syncthreads();

  float* out_boxes  = out;
  float* out_scores = out + (size_t)BATCH * TOTK * 4;
  float* out_labels = out + (size_t)BATCH * TOTK * 5;
  bool kp = (skeep[t >> 6] >> (t & 63)) & 1ull;
  int gi = img * TOTK + t;
  out_boxes[gi*4+0] = kp ? sbx[p*4+0] : 0.0f;
  out_boxes[gi*4+1] = kp ? sbx[p*4+1] : 0.0f;
  out_boxes[gi*4+2] = kp ? sbx[p*4+2] : 0.0f;
  out_boxes[gi*4+3] = kp ? sbx[p*4+3] : 0.0f;
  out_scores[gi] = kp ? sc_r : 0.0f;
  out_labels[gi] = kp ? (float)lb_r : -1.0f;
}

extern "C" void kernel_launch(void* const* d_in, const int* in_sizes, int n_in,
                              void* d_out, int out_size, void* d_ws, size_t ws_size,
                              hipStream_t stream) {
  const float* obj8  = (const float*)d_in[0];
  const float* cls8  = (const float*)d_in[1];
  const float* reg8  = (const float*)d_in[2];
  const float* obj16 = (const float*)d_in[3];
  const float* cls16 = (const float*)d_in[4];
  const float* reg16 = (const float*)d_in[5];
  const float* obj32 = (const float*)d_in[6];
  const float* cls32 = (const float*)d_in[7];
  const float* reg32 = (const float*)d_in[8];

  // ws layout: part (2688*64 u64 = 1.376 MB) | score | label | box
  u64*   ws_part  = (u64*)d_ws;
  char*  base     = (char*)d_ws + (size_t)BATCH * NCH * TOPK * sizeof(u64);
  float* ws_score = (float*)base;
  int*   ws_label = (int*)(base + (size_t)BATCH * TOTK * sizeof(float));
  float* ws_box   = (float*)(base + (size_t)BATCH * TOTK * 2 * sizeof(float));

  scan_kernel<<<dim3(BATCH * NCH), dim3(256), 0, stream>>>(
      obj8, cls8, obj16, cls16, obj32, cls32, ws_part);
  merge_kernel<<<dim3(BATCH * 3), dim3(256), 0, stream>>>(
      ws_part, reg8, reg16, reg32, ws_score, ws_label, ws_box);
  nms_kernel<<<dim3(BATCH), dim3(192), 0, stream>>>(
      ws_score, ws_label, ws_box, (float*)d_out);
}

// Round 5
// 287.609 us; speedup vs baseline: 1.1580x; 1.1580x over previous
//
#include <hip/hip_runtime.h>

// YOLO post-process, 3 kernels:
//  scan : per (img, 1600-anchor chunk) exact streaming top-64, float4 loads,
//         shuffle seed threshold, LDS candidate buffer. ALL register arrays
//         statically indexed (R4's runtime index spilled 170 MB to scratch).
//  merge: per (img, level) sort chunk top-64s -> level top-64, decode boxes
//  nms  : per img stable sort 192 + parallel IoU bit-matrix + greedy bit-sweep

#define NUM_CLASSES 5
#define CONF_THRESH 0.6f
#define NMS_THRESH  0.2f
#define TOPK   64
#define BATCH  128
#define TOTK   192
#define NCH    21      // per image: 16 (lvl0) + 4 (lvl1) + 1 (lvl2), 1600 anchors each
#define CHUNK  1600
#define SCAP   2048    // LDS candidate buffer (u64)
#define SOFT   768     // compact when cnt exceeds this; SOFT + 1280 <= SCAP

typedef unsigned long long u64;
typedef unsigned int u32;

// Descending bitonic sort of k[0..m) (m pow2), block-cooperative.
// First action is a barrier (covers preceding LDS writes); ends with a barrier.
__device__ void bitonic_desc(u64* k, int m) {
  for (int kk = 2; kk <= m; kk <<= 1) {
    for (int j = kk >> 1; j > 0; j >>= 1) {
      __syncthreads();
      for (int i = threadIdx.x; i < m; i += blockDim.x) {
        int ixj = i ^ j;
        if (ixj > i) {
          u64 a = k[i], b = k[ixj];
          bool sw = ((i & kk) == 0) ? (a < b) : (a > b);
          if (sw) { k[i] = b; k[ixj] = a; }
        }
      }
    }
  }
  __syncthreads();
}

// In-register bitonic sort of 64 values across one wave, descending by lane.
__device__ inline u64 wave_sort64_desc(u64 v, int lane) {
  #pragma unroll
  for (int k = 2; k <= 64; k <<= 1) {
    #pragma unroll
    for (int j = k >> 1; j > 0; j >>= 1) {
      u64 o = __shfl_xor(v, j, 64);
      bool keepMax = (((lane & k) == 0) != ((lane & j) != 0));
      v = keepMax ? (v > o ? v : o) : (v < o ? v : o);
    }
  }
  return v;
}

// score = sqrt(sigmoid(obj)*sigmoid(cls)); key = (score_bits<<32) | ~idx
// reproduces lax.top_k order (value desc, index asc). Bit-exact vs numpy
// (absmax 0.0 R2-R4) -- do not alter the float expressions.
__device__ inline u64 score_key(float so, float cv, int idx) {
  float sc = 1.0f / (1.0f + expf(-cv));
  float s  = sqrtf(__fmul_rn(so, sc));
  return ((u64)__float_as_uint(s) << 32) | (u32)(~(u32)idx);
}

__device__ inline float sigmoidf(float x) { return 1.0f / (1.0f + expf(-x)); }

__global__ __launch_bounds__(256) void scan_kernel(
    const float* __restrict__ obj8,  const float* __restrict__ cls8,
    const float* __restrict__ obj16, const float* __restrict__ cls16,
    const float* __restrict__ obj32, const float* __restrict__ cls32,
    u64* __restrict__ ws_part) {
  __shared__ u64 keys[SCAP];
  __shared__ int cnt;
  __shared__ u64 sthr[4];

  const int bx  = blockIdx.x;
  const int img = bx / NCH;
  const int c   = bx - img * NCH;
  const int t   = threadIdx.x;
  const int lane = t & 63, wv = t >> 6;

  const float *obj, *cls;
  int hw, off;
  if (c < 16)      { obj = obj8;  cls = cls8;  hw = 25600; off = c * CHUNK; }
  else if (c < 20) { obj = obj16; cls = cls16; hw = 6400;  off = (c - 16) * CHUNK; }
  else             { obj = obj32; cls = cls32; hw = 1600;  off = 0; }
  obj += (size_t)img * hw + off;
  cls += ((size_t)img * hw + off) * NUM_CLASSES;

  // ---- phase 1: anchors [0,1024), thread t owns 4 consecutive anchors.
  // kk[] is ONLY ever indexed by compile-time constants (full unroll) so it
  // stays in VGPRs. (R4 lesson: one runtime index -> whole array in scratch.)
  u64 kk[20];
  u64 mx;
  {
    const float4* c4 = (const float4*)cls + (size_t)t * 5;
    float4 q0 = c4[0], q1 = c4[1], q2 = c4[2], q3 = c4[3], q4 = c4[4];
    float4 ov = ((const float4*)obj)[t];
    float cv[20] = { q0.x,q0.y,q0.z,q0.w, q1.x,q1.y,q1.z,q1.w,
                     q2.x,q2.y,q2.z,q2.w, q3.x,q3.y,q3.z,q3.w,
                     q4.x,q4.y,q4.z,q4.w };
    float os[4] = { sigmoidf(ov.x), sigmoidf(ov.y), sigmoidf(ov.z), sigmoidf(ov.w) };
    int ga0 = off + 4 * t;
    #pragma unroll
    for (int a = 0; a < 4; ++a)
      #pragma unroll
      for (int j = 0; j < 5; ++j)
        kk[a * 5 + j] = score_key(os[a], cv[a * 5 + j], (ga0 + a) * NUM_CLASSES + j);
    mx = kk[0];
    #pragma unroll
    for (int i = 1; i < 20; ++i) if (kk[i] > mx) mx = kk[i];
  }
  // seed threshold: min over waves of (wave's 16th-largest thread-max).
  // Each wave has >=16 real keys >= its 16th -> >=64 keys >= seed overall.
  u64 srt = wave_sort64_desc(mx, lane);
  if (lane == 15) sthr[wv] = srt;
  if (t == 0) cnt = 0;
  __syncthreads();
  u64 thr;
  {
    u64 a0 = sthr[0], a1 = sthr[1], a2 = sthr[2], a3 = sthr[3];
    u64 mn = a0 < a1 ? a0 : a1;
    u64 mn2 = a2 < a3 ? a2 : a3;
    thr = (mn < mn2 ? mn : mn2) - 1ull;   // push iff key > thr  (key >= seed)
  }

  int cs = 0;
  // ---- push rounds 0..3 from retained kk (anchors [0,1024)) ----
  #pragma unroll
  for (int a = 0; a < 4; ++a) {
    #pragma unroll
    for (int j = 0; j < 5; ++j) {
      u64 key = kk[a * 5 + j];
      if (key > thr) { int p = atomicAdd(&cnt, 1); if (p < SCAP) keys[p] = key; }
    }
    __syncthreads();
    cs = cnt;
    __syncthreads();              // uniform snapshot before further pushes
    if (cs > SOFT) {              // rare: compact to top-64, tighten threshold
      int m = 64; while (m < cs) m <<= 1;
      for (int i = cs + t; i < m; i += 256) keys[i] = 0ull;
      bitonic_desc(keys, m);
      if (t == 0) cnt = TOPK;
      u64 nt = keys[TOPK - 1];
      __syncthreads();
      thr = nt; cs = TOPK;
    }
  }

  // ---- phase 2: anchors [1024,1600) (576), threads t<144, rounds 4..7 ----
  const bool act2 = (t < 144);
  if (act2) {
    const float4* c4 = (const float4*)cls + 1280 + (size_t)t * 5;
    float4 q0 = c4[0], q1 = c4[1], q2 = c4[2], q3 = c4[3], q4 = c4[4];
    float4 ov = ((const float4*)obj)[256 + t];
    float cv[20] = { q0.x,q0.y,q0.z,q0.w, q1.x,q1.y,q1.z,q1.w,
                     q2.x,q2.y,q2.z,q2.w, q3.x,q3.y,q3.z,q3.w,
                     q4.x,q4.y,q4.z,q4.w };
    float os[4] = { sigmoidf(ov.x), sigmoidf(ov.y), sigmoidf(ov.z), sigmoidf(ov.w) };
    int ga0 = off + 1024 + 4 * t;
    #pragma unroll
    for (int a = 0; a < 4; ++a)
      #pragma unroll
      for (int j = 0; j < 5; ++j)
        kk[a * 5 + j] = score_key(os[a], cv[a * 5 + j], (ga0 + a) * NUM_CLASSES + j);
  }
  #pragma unroll
  for (int a = 0; a < 4; ++a) {
    if (act2) {
      #pragma unroll
      for (int j = 0; j < 5; ++j) {
        u64 key = kk[a * 5 + j];
        if (key > thr) { int p = atomicAdd(&cnt, 1); if (p < SCAP) keys[p] = key; }
      }
    }
    __syncthreads();
    cs = cnt;
    __syncthreads();
    if (cs > SOFT) {
      int m = 64; while (m < cs) m <<= 1;
      for (int i = cs + t; i < m; i += 256) keys[i] = 0ull;
      bitonic_desc(keys, m);
      if (t == 0) cnt = TOPK;
      u64 nt = keys[TOPK - 1];
      __syncthreads();
      thr = nt; cs = TOPK;
    }
  }

  // ---- final sort, emit chunk top-64 (cnt >= 64 guaranteed by seed) ----
  {
    int m = 64; while (m < cs) m <<= 1;
    for (int i = cs + t; i < m; i += 256) keys[i] = 0ull;
    bitonic_desc(keys, m);
  }
  if (t < TOPK) ws_part[(size_t)bx * TOPK + t] = keys[t];
}

// One block per (img, level): sort nchunk*64 keys, keep 64, decode boxes.
__global__ __launch_bounds__(256) void merge_kernel(
    const u64* __restrict__ ws_part,
    const float* __restrict__ reg8, const float* __restrict__ reg16, const float* __restrict__ reg32,
    float* __restrict__ ws_score, int* __restrict__ ws_label, float* __restrict__ ws_box) {
  __shared__ u64 keys[1024];
  const int bx  = blockIdx.x;
  const int img = bx / 3;
  const int lvl = bx - img * 3;
  const int tid = threadIdx.x;

  const float* reg; int nchunk, cbase, w, hw; float stride;
  if (lvl == 0)      { reg = reg8;  nchunk = 16; cbase = 0;  w = 160; hw = 25600; stride = 8.0f;  }
  else if (lvl == 1) { reg = reg16; nchunk = 4;  cbase = 16; w = 80;  hw = 6400;  stride = 16.0f; }
  else               { reg = reg32; nchunk = 1;  cbase = 20; w = 40;  hw = 1600;  stride = 32.0f; }
  reg += (size_t)img * hw * 4;
  const int nk = nchunk * TOPK;                     // 1024 / 256 / 64 (pow2)
  const u64* src = ws_part + ((size_t)img * NCH + cbase) * TOPK;
  for (int i = tid; i < nk; i += 256) keys[i] = src[i];
  bitonic_desc(keys, nk);

  if (tid < TOPK) {
    u64 key = keys[tid];
    float s = __uint_as_float((u32)(key >> 32));
    u32 idx = ~((u32)key);
    int a = (int)(idx / NUM_CLASSES);
    int c = (int)(idx - (u32)a * NUM_CLASSES);
    int ix = a % w, iy = a / w;
    float ax = __fmul_rn((float)ix + 0.5f, stride);
    float ay = __fmul_rn((float)iy + 0.5f, stride);
    float r0 = reg[a*4+0], r1 = reg[a*4+1], r2 = reg[a*4+2], r3 = reg[a*4+3];
    float cx = __fadd_rn(__fmul_rn(r0, stride), ax);
    float cy = __fadd_rn(__fmul_rn(r1, stride), ay);
    float wd = __fmul_rn(expf(r2), stride);
    float ht = __fmul_rn(expf(r3), stride);
    float x1 = __fsub_rn(cx, __fmul_rn(0.5f, wd));
    float y1 = __fsub_rn(cy, __fmul_rn(0.5f, ht));
    float x2 = __fadd_rn(cx, __fmul_rn(0.5f, wd));
    float y2 = __fadd_rn(cy, __fmul_rn(0.5f, ht));
    int gi = img * TOTK + lvl * TOPK + tid;
    ws_score[gi] = s;
    ws_label[gi] = c;
    ws_box[gi*4+0] = x1; ws_box[gi*4+1] = y1;
    ws_box[gi*4+2] = x2; ws_box[gi*4+3] = y2;
  }
}

// One block (192 threads) per image.
__global__ __launch_bounds__(192) void nms_kernel(
    const float* __restrict__ ws_score, const int* __restrict__ ws_label,
    const float* __restrict__ ws_box, float* __restrict__ out) {
  __shared__ u64   skeys[256];
  __shared__ int   slb[TOTK];
  __shared__ float sbx[TOTK * 4];
  __shared__ float sX1[TOTK], sY1[TOTK], sX2[TOTK], sY2[TOTK], sA[TOTK];
  __shared__ u64   rows[TOTK * 3];
  __shared__ u64   svalid[3];
  __shared__ u64   skeep[3];
  __shared__ float lmarr[3];

  const int t   = threadIdx.x;
  const int img = blockIdx.x;

  {
    int gi = img * TOTK + t;
    float sc = ws_score[gi];
    int   lb = ws_label[gi];
    float b0 = ws_box[gi*4+0], b1 = ws_box[gi*4+1];
    float b2 = ws_box[gi*4+2], b3 = ws_box[gi*4+3];
    slb[t] = lb;
    sbx[t*4+0] = b0; sbx[t*4+1] = b1; sbx[t*4+2] = b2; sbx[t*4+3] = b3;
    skeys[t] = ((u64)__float_as_uint(sc) << 32) | (u32)(~(u32)t);
    if (t < 64) skeys[TOTK + t] = 0ull;
    float lm = fmaxf(fmaxf(fabsf(b0), fabsf(b1)), fmaxf(fabsf(b2), fabsf(b3)));
    #pragma unroll
    for (int d = 32; d > 0; d >>= 1) lm = fmaxf(lm, __shfl_xor(lm, d, 64));
    if ((t & 63) == 0) lmarr[t >> 6] = lm;
  }
  bitonic_desc(skeys, 256);

  const float lmAll = fmaxf(fmaxf(lmarr[0], lmarr[1]), lmarr[2]);
  const float offscale = __fadd_rn(__fmul_rn(2.0f, lmAll), 1.0f);

  u64 key = skeys[t];
  int p = (int)(~((u32)key)) & 255;
  float sc_r = __uint_as_float((u32)(key >> 32));
  int lb_r = slb[p];
  float off = __fmul_rn((float)lb_r, offscale);
  float X1 = __fadd_rn(sbx[p*4+0], off), Y1 = __fadd_rn(sbx[p*4+1], off);
  float X2 = __fadd_rn(sbx[p*4+2], off), Y2 = __fadd_rn(sbx[p*4+3], off);
  float A  = __fmul_rn(__fsub_rn(X2, X1), __fsub_rn(Y2, Y1));
  sX1[t] = X1; sY1[t] = Y1; sX2[t] = X2; sY2[t] = Y2; sA[t] = A;
  {
    u64 bal = __ballot(sc_r > CONF_THRESH);
    if ((t & 63) == 0) svalid[t >> 6] = bal;
  }
  __syncthreads();

  {
    u64 r0 = 0, r1 = 0, r2 = 0;
    for (int j = t + 1; j < TOTK; ++j) {
      float xx1 = fmaxf(X1, sX1[j]);
      float yy1 = fmaxf(Y1, sY1[j]);
      float xx2 = fminf(X2, sX2[j]);
      float yy2 = fminf(Y2, sY2[j]);
      float wv = fmaxf(1e-10f, __fsub_rn(xx2, xx1));
      float hv = fmaxf(1e-10f, __fsub_rn(yy2, yy1));
      float inter = __fmul_rn(wv, hv);
      float den = __fsub_rn(__fadd_rn(A, sA[j]), inter);
      float iou = __fdiv_rn(inter, den);
      if (iou > NMS_THRESH) {
        u64 b = 1ull << (j & 63);
        int wd = j >> 6;
        r0 |= (wd == 0) ? b : 0ull;
        r1 |= (wd == 1) ? b : 0ull;
        r2 |= (wd == 2) ? b : 0ull;
      }
    }
    rows[t*3+0] = r0; rows[t*3+1] = r1; rows[t*3+2] = r2;
  }
  __syncthreads();

  if (t < 64) {
    u64 k0 = svalid[0], k1 = svalid[1], k2 = svalid[2];
    #pragma unroll 4
    for (int i = 0; i < 64; ++i) {
      u64 m0 = rows[i*3+0], m1 = rows[i*3+1], m2 = rows[i*3+2];
      u64 sel = 0ull - ((k0 >> i) & 1ull);
      k0 &= ~(m0 & sel); k1 &= ~(m1 & sel); k2 &= ~(m2 & sel);
    }
    #pragma unroll 4
    for (int i = 0; i < 64; ++i) {
      int r = 64 + i;
      u64 m0 = rows[r*3+0], m1 = rows[r*3+1], m2 = rows[r*3+2];
      u64 sel = 0ull - ((k1 >> i) & 1ull);
      k0 &= ~(m0 & sel); k1 &= ~(m1 & sel); k2 &= ~(m2 & sel);
    }
    #pragma unroll 4
    for (int i = 0; i < 64; ++i) {
      int r = 128 + i;
      u64 m0 = rows[r*3+0], m1 = rows[r*3+1], m2 = rows[r*3+2];
      u64 sel = 0ull - ((k2 >> i) & 1ull);
      k0 &= ~(m0 & sel); k1 &= ~(m1 & sel); k2 &= ~(m2 & sel);
    }
    if (t == 0) { skeep[0] = k0; skeep[1] = k1; skeep[2] = k2; }
  }
  __syncthreads();

  float* out_boxes  = out;
  float* out_scores = out + (size_t)BATCH * TOTK * 4;
  float* out_labels = out + (size_t)BATCH * TOTK * 5;
  bool kp = (skeep[t >> 6] >> (t & 63)) & 1ull;
  int gi = img * TOTK + t;
  out_boxes[gi*4+0] = kp ? sbx[p*4+0] : 0.0f;
  out_boxes[gi*4+1] = kp ? sbx[p*4+1] : 0.0f;
  out_boxes[gi*4+2] = kp ? sbx[p*4+2] : 0.0f;
  out_boxes[gi*4+3] = kp ? sbx[p*4+3] : 0.0f;
  out_scores[gi] = kp ? sc_r : 0.0f;
  out_labels[gi] = kp ? (float)lb_r : -1.0f;
}

extern "C" void kernel_launch(void* const* d_in, const int* in_sizes, int n_in,
                              void* d_out, int out_size, void* d_ws, size_t ws_size,
                              hipStream_t stream) {
  const float* obj8  = (const float*)d_in[0];
  const float* cls8  = (const float*)d_in[1];
  const float* reg8  = (const float*)d_in[2];
  const float* obj16 = (const float*)d_in[3];
  const float* cls16 = (const float*)d_in[4];
  const float* reg16 = (const float*)d_in[5];
  const float* obj32 = (const float*)d_in[6];
  const float* cls32 = (const float*)d_in[7];
  const float* reg32 = (const float*)d_in[8];

  // ws layout: part (2688*64 u64 = 1.376 MB) | score | label | box
  u64*   ws_part  = (u64*)d_ws;
  char*  base     = (char*)d_ws + (size_t)BATCH * NCH * TOPK * sizeof(u64);
  float* ws_score = (float*)base;
  int*   ws_label = (int*)(base + (size_t)BATCH * TOTK * sizeof(float));
  float* ws_box   = (float*)(base + (size_t)BATCH * TOTK * 2 * sizeof(float));

  scan_kernel<<<dim3(BATCH * NCH), dim3(256), 0, stream>>>(
      obj8, cls8, obj16, cls16, obj32, cls32, ws_part);
  merge_kernel<<<dim3(BATCH * 3), dim3(256), 0, stream>>>(
      ws_part, reg8, reg16, reg32, ws_score, ws_label, ws_box);
  nms_kernel<<<dim3(BATCH), dim3(192), 0, stream>>>(
      ws_score, ws_label, ws_box, (float*)d_out);
}